// Round 8
// baseline (1464.426 us; speedup 1.0000x reference)
//
#include <hip/hip_runtime.h>
#include <stdint.h>

// NBEATS seasonal KAN block — persistent mega-kernel (256 blocks x 512 thr),
// software grid barrier (sense-reversal, device-scope). 2 dispatches total:
// memset(bar) + mega. Phases: setup+expand0 | 4x(GEMM;expand) | thetaGEMM | proj.

typedef unsigned short u16;
typedef __attribute__((ext_vector_type(8))) short short8;   // 8 bf16
typedef __attribute__((ext_vector_type(4))) float f32x4;    // MFMA accum

#define NB 2048
#define KD 4608
#define NTH 128
#define NTT 640
#define GRID 256

__device__ __forceinline__ u16 f2bf(float f) {
  union { float f; uint32_t u; } c; c.f = f;
  return (u16)((c.u + 0x7FFFu + ((c.u >> 16) & 1u)) >> 16);   // RNE
}

__device__ __forceinline__ void load_lds16(const void* g, void* lds) {
  __builtin_amdgcn_global_load_lds((const __attribute__((address_space(1))) void*)g,
                                   (__attribute__((address_space(3))) void*)lds, 16, 0, 0);
}

// ---------- software grid barrier ----------
__device__ __forceinline__ void gbar(int* bar) {
  __threadfence();                     // each thread publishes its writes (wb L2)
  __syncthreads();
  if (threadIdx.x == 0) {
    const int gen = __hip_atomic_load(&bar[1], __ATOMIC_ACQUIRE, __HIP_MEMORY_SCOPE_AGENT);
    const int t   = __hip_atomic_fetch_add(&bar[0], 1, __ATOMIC_ACQ_REL, __HIP_MEMORY_SCOPE_AGENT);
    if (t == GRID - 1) {
      __hip_atomic_store(&bar[0], 0, __ATOMIC_RELAXED, __HIP_MEMORY_SCOPE_AGENT);
      __hip_atomic_fetch_add(&bar[1], 1, __ATOMIC_ACQ_REL, __HIP_MEMORY_SCOPE_AGENT);
    } else {
      while (__hip_atomic_load(&bar[1], __ATOMIC_ACQUIRE, __HIP_MEMORY_SCOPE_AGENT) == gen)
        __builtin_amdgcn_s_sleep(2);
    }
  }
  __syncthreads();
  __threadfence();                     // invalidate stale caches before next phase reads
}

// ---------- bspline (K=3, NUM=5, uniform grid g[j]=0.4j-2.2), div-free ----------
__device__ __forceinline__ void bspline8(float x, float* v8) {
  float g[12];
  #pragma unroll
  for (int j = 0; j < 12; ++j) g[j] = (float)((j - 3) * 0.4 - 1.0);
  float w[11];
  #pragma unroll
  for (int j = 0; j < 11; ++j) w[j] = (x >= g[j] && x < g[j+1]) ? 1.0f : 0.0f;
  #pragma unroll
  for (int p = 1; p <= 3; ++p) {
    #pragma unroll
    for (int j = 0; j < 11 - p; ++j) {
      const float i1 = 1.0f / (g[j+p] - g[j]);
      const float i2 = 1.0f / (g[j+p+1] - g[j+1]);
      w[j] = (x - g[j]) * i1 * w[j] + (g[j+p+1] - x) * i2 * w[j+1];
    }
  }
  #pragma unroll
  for (int j = 0; j < 8; ++j) v8[j] = w[j];
}

__device__ __forceinline__ void expand_quad(const float* xv, u16* __restrict__ row, int i0) {
  float base[4], v[4][8];
  #pragma unroll
  for (int e = 0; e < 4; ++e) {
    base[e] = xv[e] / (1.0f + __expf(-xv[e]));   // silu
    bspline8(xv[e], v[e]);
  }
  short4 s;
  s.x = (short)f2bf(base[0]); s.y = (short)f2bf(base[1]);
  s.z = (short)f2bf(base[2]); s.w = (short)f2bf(base[3]);
  *(short4*)(row + i0) = s;
  #pragma unroll
  for (int f = 0; f < 8; ++f) {
    s.x = (short)f2bf(v[0][f]); s.y = (short)f2bf(v[1][f]);
    s.z = (short)f2bf(v[2][f]); s.w = (short)f2bf(v[3][f]);
    *(short4*)(row + (1 + f) * 512 + i0) = s;
  }
}

// ---------- weight-pack one 64x64 tile via LDS transpose (512 threads) ----------
__device__ __forceinline__ void pack_tile(const float* __restrict__ coef,
                                          const float* __restrict__ sb,
                                          const float* __restrict__ ssp,
                                          u16* __restrict__ Wt, u16* T,
                                          int l, int i0, int o0, int O) {
  const int tid = threadIdx.x;
  #pragma unroll 2
  for (int pass = 0; pass < 8; ++pass) {       // read: lanes along o (coalesced)
    const int o_loc = tid & 63;
    const int i_loc = pass * 8 + (tid >> 6);
    const size_t io = ((size_t)l * 512 + i0 + i_loc) * (size_t)O + o0 + o_loc;
    const float sspv = ssp[io];
    const float4 a = *(const float4*)(coef + io * 8);
    const float4 b = *(const float4*)(coef + io * 8 + 4);
    u16* t0 = T + i_loc * 66 + o_loc;
    t0[0 * 64 * 66] = f2bf(sb[io]);
    t0[1 * 64 * 66] = f2bf(a.x * sspv);
    t0[2 * 64 * 66] = f2bf(a.y * sspv);
    t0[3 * 64 * 66] = f2bf(a.z * sspv);
    t0[4 * 64 * 66] = f2bf(a.w * sspv);
    t0[5 * 64 * 66] = f2bf(b.x * sspv);
    t0[6 * 64 * 66] = f2bf(b.y * sspv);
    t0[7 * 64 * 66] = f2bf(b.z * sspv);
    t0[8 * 64 * 66] = f2bf(b.w * sspv);
  }
  __syncthreads();
  #pragma unroll
  for (int f = 0; f < 9; ++f)                  // write: lanes along i (coalesced)
    #pragma unroll 2
    for (int pass = 0; pass < 8; ++pass) {
      const int i_loc = tid & 63;
      const int o_loc = pass * 8 + (tid >> 6);
      Wt[((size_t)l * O + o0 + o_loc) * KD + f * 512 + i0 + i_loc] =
          T[(f * 64 + i_loc) * 66 + o_loc];
    }
}

// ---------- GEMM: 128x128 tile, BK=64, 8 waves, 3-deep counted vmcnt ----------
__device__ __forceinline__ void stage_tile8(const u16* __restrict__ A, const u16* __restrict__ Bt,
                                            u16* As, u16* Bs, int rowBase, int colBase,
                                            int kOff, int wave, int lane) {
  const int sRow   = lane >> 3;
  const int sChunk = (lane & 7) ^ sRow;        // pre-swizzled global 16B chunk
  #pragma unroll
  for (int j = 0; j < 2; ++j) {
    const int slot = wave * 16 + j * 8;        // 8 rows / gload_lds
    load_lds16(A  + (size_t)(rowBase + slot + sRow) * KD + kOff + sChunk * 8, As + slot * 64);
    load_lds16(Bt + (size_t)(colBase + slot + sRow) * KD + kOff + sChunk * 8, Bs + slot * 64);
  }
}

__device__ __forceinline__ void mma_step8(const u16* As, const u16* Bs, f32x4 acc[4][2],
                                          int wr, int wc, int lane) {
  const int lr = lane & 15, lk8 = lane >> 4;
  #pragma unroll
  for (int ks = 0; ks < 2; ++ks) {
    short8 af[4], bf[2];
    const int kc = ks * 4 + lk8;
    #pragma unroll
    for (int m = 0; m < 4; ++m) {
      const int r = wr * 64 + m * 16 + lr;
      af[m] = *(const short8*)(As + r * 64 + ((kc ^ (r & 7)) * 8));
    }
    #pragma unroll
    for (int n = 0; n < 2; ++n) {
      const int r = wc * 32 + n * 16 + lr;
      bf[n] = *(const short8*)(Bs + r * 64 + ((kc ^ (r & 7)) * 8));
    }
    #pragma unroll
    for (int m = 0; m < 4; ++m)
      #pragma unroll
      for (int n = 0; n < 2; ++n)
        acc[m][n] = __builtin_amdgcn_mfma_f32_16x16x32_bf16(af[m], bf[n], acc[m][n], 0, 0, 0);
  }
}

template<int N, int KITER>
__device__ __forceinline__ void gemm_job8(const u16* __restrict__ A, const u16* __restrict__ Bt,
                                          float* __restrict__ Cp, int bx, int by, int bz,
                                          u16* sm) {
  const int tid  = threadIdx.x;
  const int wave = tid >> 6, lane = tid & 63;
  const int rowBase = bx * 128, colBase = by * 128;
  const int kb0 = bz * KITER;
  const int wr = wave >> 2, wc = wave & 3;     // 2x4 wave grid: 64x32 each

  u16 *Ac = sm,             *Bc = sm + 8192;
  u16 *An = sm + 2 * 8192,  *Bn = sm + 3 * 8192;
  u16 *Af = sm + 4 * 8192,  *Bf = sm + 5 * 8192;

  f32x4 acc[4][2] = {};

  stage_tile8(A, Bt, Ac, Bc, rowBase, colBase, (kb0 + 0) * 64, wave, lane);
  stage_tile8(A, Bt, An, Bn, rowBase, colBase, (kb0 + 1) * 64, wave, lane);

  for (int t = 0; t < KITER - 1; ++t) {
    asm volatile("s_waitcnt vmcnt(4)" ::: "memory");   // tile t done; t+1 in flight
    __builtin_amdgcn_s_barrier();
    if (t + 2 < KITER)
      stage_tile8(A, Bt, Af, Bf, rowBase, colBase, (kb0 + t + 2) * 64, wave, lane);
    mma_step8(Ac, Bc, acc, wr, wc, lane);
    __builtin_amdgcn_s_barrier();
    u16* tp;
    tp = Ac; Ac = An; An = Af; Af = tp;
    tp = Bc; Bc = Bn; Bn = Bf; Bf = tp;
  }
  asm volatile("s_waitcnt vmcnt(0)" ::: "memory");
  __builtin_amdgcn_s_barrier();
  mma_step8(Ac, Bc, acc, wr, wc, lane);

  float* out = Cp + (size_t)bz * (size_t)NB * N;
  #pragma unroll
  for (int m = 0; m < 4; ++m) {
    const int row0 = rowBase + wr * 64 + m * 16 + (lane >> 4) * 4;   // row=(l>>4)*4+reg
    #pragma unroll
    for (int n = 0; n < 2; ++n) {
      const int col = colBase + wc * 32 + n * 16 + (lane & 15);      // col=l&15
      #pragma unroll
      for (int r = 0; r < 4; ++r)
        out[(size_t)(row0 + r) * N + col] = acc[m][n][r];
    }
  }
}

// ---------- mega ----------
__global__ __launch_bounds__(512)
void mega(const float* __restrict__ x,
          const float* __restrict__ coef_fc, const float* __restrict__ sb_fc,
          const float* __restrict__ ssp_fc,  const float* __restrict__ coef_th,
          const float* __restrict__ sb_th,   const float* __restrict__ ssp_th,
          float* __restrict__ out, int* __restrict__ bar,
          u16* __restrict__ WtFc, u16* __restrict__ WtTh, u16* __restrict__ Act,
          float* __restrict__ Part, float* __restrict__ S) {
  const int tid = threadIdx.x, blk = blockIdx.x;
  __shared__ __align__(16) u16 sm[6 * 8192];   // 96 KiB (GEMM 3x dbuf / pack T / proj Ts)

  // ---- phase A: weight pack + S + expand0 ----
  {
    const int l  = blk >> 6;
    const int i0 = ((blk >> 3) & 7) * 64;
    const int o0 = (blk & 7) * 64;
    pack_tile(coef_fc, sb_fc, ssp_fc, WtFc, sm, l, i0, o0, 512);
    if (blk < 16) {
      __syncthreads();
      pack_tile(coef_th, sb_th, ssp_th, WtTh, sm, 0, (blk >> 1) * 64, (blk & 1) * 64, 128);
    } else if (blk < 36) {
      const int base = (blk - 16) * 4096;
      #pragma unroll
      for (int q = 0; q < 8; ++q) {
        const int id = base + q * 512 + tid;   // < 81920 = 128*640
        const int j = id & 127, t = id >> 7;
        const int m = ((j & 63) * t) % 63;
        const float ang = (float)(6.283185307179586 * (double)m / 63.0);
        S[(size_t)j * NTT + t] = (j < 64) ? cosf(ang) : sinf(ang);
      }
    }
    #pragma unroll
    for (int q = 0; q < 2; ++q) {              // expand0
      const int qid = blk * 1024 + q * 512 + tid;
      const int b = qid >> 7, i0q = (qid & 127) * 4;
      const float4 v = *(const float4*)(x + (size_t)qid * 4);
      float xv[4] = {v.x, v.y, v.z, v.w};
      expand_quad(xv, Act + (size_t)b * KD, i0q);
    }
  }
  gbar(bar);

  // ---- fc layers: 256 GEMM jobs (16bx x 4by x 4bz, XCD swizzle), then expand ----
  for (int l = 0; l < 4; ++l) {
    {
      const int xcd = blk & 7;
      const int bz  = xcd >> 1;
      const int u   = blk >> 3;
      const int bx  = ((u & 7) << 1) | (xcd & 1);
      const int by  = u >> 3;
      gemm_job8<512, 18>(Act, WtFc + (size_t)l * 512 * KD, Part, bx, by, bz, sm);
    }
    gbar(bar);
    #pragma unroll
    for (int q = 0; q < 2; ++q) {
      const int qid = blk * 1024 + q * 512 + tid;
      const int b = qid >> 7, i0q = (qid & 127) * 4;
      float xv[4] = {0.f, 0.f, 0.f, 0.f};
      #pragma unroll
      for (int t = 0; t < 4; ++t) {
        const float4 v = *(const float4*)(Part + (size_t)t * NB * 512 + (size_t)qid * 4);
        xv[0] += v.x; xv[1] += v.y; xv[2] += v.z; xv[3] += v.w;
      }
      expand_quad(xv, Act + (size_t)b * KD, i0q);
    }
    gbar(bar);
  }

  // ---- theta GEMM: 128 jobs (16bx x 8bz), kIter 9 ----
  if (blk < 128)
    gemm_job8<NTH, 9>(Act, WtTh, Part, blk & 15, 0, blk >> 4, sm);
  gbar(bar);

  // ---- proj (+8-partial theta reduce): 320 jobs ----
  float* Ts = (float*)sm;                      // [64][129] fp32 = 33 KB
  #pragma unroll
  for (int jq = 0; jq < 2; ++jq) {
    const int j = blk + jq * 256;
    if (j >= 320) break;
    const int brow = (j & 31) * 64, bcol = (j >> 5) * 64;
    for (int idx = tid; idx < 64 * 128; idx += 512) {
      const int r = idx >> 7, c = idx & 127;
      float s = 0.f;
      #pragma unroll
      for (int t = 0; t < 8; ++t)
        s += Part[(size_t)t * NB * NTH + (size_t)(brow + r) * NTH + c];
      Ts[r * 129 + c] = s;
    }
    __syncthreads();
    const int tx = tid & 15, ty = tid >> 4;    // 16 x 32
    const int r0 = ty * 2, c0 = tx * 4;
    float acc[2][4] = {};
    for (int k = 0; k < 128; ++k) {
      const float4 sv = *(const float4*)(S + (size_t)k * NTT + bcol + c0);
      #pragma unroll
      for (int rr = 0; rr < 2; ++rr) {
        const float tv = Ts[(r0 + rr) * 129 + k];
        acc[rr][0] += tv * sv.x; acc[rr][1] += tv * sv.y;
        acc[rr][2] += tv * sv.z; acc[rr][3] += tv * sv.w;
      }
    }
    #pragma unroll
    for (int rr = 0; rr < 2; ++rr) {
      const int b = brow + r0 + rr;
      #pragma unroll
      for (int cc = 0; cc < 4; ++cc) {
        const int t = bcol + c0 + cc;
        if (t < 512) out[(size_t)b * 512 + t] = acc[rr][cc];                            // backcast
        else         out[(size_t)NB * 512 + (size_t)b * NTH + (t - 512)] = acc[rr][cc]; // forecast
      }
    }
    __syncthreads();
  }
}

extern "C" void kernel_launch(void* const* d_in, const int* in_sizes, int n_in,
                              void* d_out, int out_size, void* d_ws, size_t ws_size,
                              hipStream_t stream) {
  (void)in_sizes; (void)n_in; (void)out_size; (void)ws_size;
  const float* x       = (const float*)d_in[0];
  const float* coef_fc = (const float*)d_in[1];
  const float* sb_fc   = (const float*)d_in[2];
  const float* ssp_fc  = (const float*)d_in[3];
  const float* coef_th = (const float*)d_in[4];
  const float* sb_th   = (const float*)d_in[5];
  const float* ssp_th  = (const float*)d_in[6];
  float* out = (float*)d_out;

  // ws: bar 256B | WtFc 18.9M | WtTh 1.18M | Act 18.9M | Part 16.8M | S 0.33M
  int*  bar  = (int*)d_ws;
  u16*  WtFc = (u16*)((char*)d_ws + 256);
  u16*  WtTh = WtFc + (size_t)4 * 512 * KD;
  u16*  Act  = WtTh + (size_t)NTH * KD;
  float* Part = (float*)(Act + (size_t)NB * KD);
  float* S    = Part + (size_t)4 * NB * 512;

  hipMemsetAsync(bar, 0, 256, stream);
  mega<<<dim3(GRID), dim3(512), 0, stream>>>(x, coef_fc, sb_fc, ssp_fc,
                                             coef_th, sb_th, ssp_th,
                                             out, bar, WtFc, WtTh, Act, Part, S);
}

// Round 9
// 469.728 us; speedup vs baseline: 3.1176x; 3.1176x over previous
//
#include <hip/hip_runtime.h>
#include <stdint.h>

// NBEATS seasonal KAN block — persistent mega-kernel (256 blocks x 512 thr).
// Round 9: identical to round 8 EXCEPT gbar uses one release-RMW / one
// acquire per BLOCK (not per-thread threadfence) + relaxed spin.

typedef unsigned short u16;
typedef __attribute__((ext_vector_type(8))) short short8;   // 8 bf16
typedef __attribute__((ext_vector_type(4))) float f32x4;    // MFMA accum

#define NB 2048
#define KD 4608
#define NTH 128
#define NTT 640
#define GRID 256

__device__ __forceinline__ u16 f2bf(float f) {
  union { float f; uint32_t u; } c; c.f = f;
  return (u16)((c.u + 0x7FFFu + ((c.u >> 16) & 1u)) >> 16);   // RNE
}

__device__ __forceinline__ void load_lds16(const void* g, void* lds) {
  __builtin_amdgcn_global_load_lds((const __attribute__((address_space(1))) void*)g,
                                   (__attribute__((address_space(3))) void*)lds, 16, 0, 0);
}

// ---------- software grid barrier (block-granular fences) ----------
__device__ __forceinline__ void gbar(int* bar) {
  __syncthreads();                 // all block writes issued & vmcnt-drained to L2
  if (threadIdx.x == 0) {
    const int gen = __hip_atomic_load(&bar[1], __ATOMIC_RELAXED, __HIP_MEMORY_SCOPE_AGENT);
    const int t   = __hip_atomic_fetch_add(&bar[0], 1, __ATOMIC_ACQ_REL, __HIP_MEMORY_SCOPE_AGENT);
    if (t == GRID - 1) {
      __hip_atomic_store(&bar[0], 0, __ATOMIC_RELAXED, __HIP_MEMORY_SCOPE_AGENT);
      __hip_atomic_store(&bar[1], gen + 1, __ATOMIC_RELEASE, __HIP_MEMORY_SCOPE_AGENT);
    } else {
      while (__hip_atomic_load(&bar[1], __ATOMIC_RELAXED, __HIP_MEMORY_SCOPE_AGENT) == gen)
        __builtin_amdgcn_s_sleep(8);
      (void)__hip_atomic_load(&bar[1], __ATOMIC_ACQUIRE, __HIP_MEMORY_SCOPE_AGENT); // one inv
    }
  }
  __syncthreads();
}

// ---------- bspline (K=3, NUM=5, uniform grid g[j]=0.4j-2.2), div-free ----------
__device__ __forceinline__ void bspline8(float x, float* v8) {
  float g[12];
  #pragma unroll
  for (int j = 0; j < 12; ++j) g[j] = (float)((j - 3) * 0.4 - 1.0);
  float w[11];
  #pragma unroll
  for (int j = 0; j < 11; ++j) w[j] = (x >= g[j] && x < g[j+1]) ? 1.0f : 0.0f;
  #pragma unroll
  for (int p = 1; p <= 3; ++p) {
    #pragma unroll
    for (int j = 0; j < 11 - p; ++j) {
      const float i1 = 1.0f / (g[j+p] - g[j]);
      const float i2 = 1.0f / (g[j+p+1] - g[j+1]);
      w[j] = (x - g[j]) * i1 * w[j] + (g[j+p+1] - x) * i2 * w[j+1];
    }
  }
  #pragma unroll
  for (int j = 0; j < 8; ++j) v8[j] = w[j];
}

__device__ __forceinline__ void expand_quad(const float* xv, u16* __restrict__ row, int i0) {
  float base[4], v[4][8];
  #pragma unroll
  for (int e = 0; e < 4; ++e) {
    base[e] = xv[e] / (1.0f + __expf(-xv[e]));   // silu
    bspline8(xv[e], v[e]);
  }
  short4 s;
  s.x = (short)f2bf(base[0]); s.y = (short)f2bf(base[1]);
  s.z = (short)f2bf(base[2]); s.w = (short)f2bf(base[3]);
  *(short4*)(row + i0) = s;
  #pragma unroll
  for (int f = 0; f < 8; ++f) {
    s.x = (short)f2bf(v[0][f]); s.y = (short)f2bf(v[1][f]);
    s.z = (short)f2bf(v[2][f]); s.w = (short)f2bf(v[3][f]);
    *(short4*)(row + (1 + f) * 512 + i0) = s;
  }
}

// ---------- weight-pack one 64x64 tile via LDS transpose (512 threads) ----------
__device__ __forceinline__ void pack_tile(const float* __restrict__ coef,
                                          const float* __restrict__ sb,
                                          const float* __restrict__ ssp,
                                          u16* __restrict__ Wt, u16* T,
                                          int l, int i0, int o0, int O) {
  const int tid = threadIdx.x;
  #pragma unroll 2
  for (int pass = 0; pass < 8; ++pass) {       // read: lanes along o (coalesced)
    const int o_loc = tid & 63;
    const int i_loc = pass * 8 + (tid >> 6);
    const size_t io = ((size_t)l * 512 + i0 + i_loc) * (size_t)O + o0 + o_loc;
    const float sspv = ssp[io];
    const float4 a = *(const float4*)(coef + io * 8);
    const float4 b = *(const float4*)(coef + io * 8 + 4);
    u16* t0 = T + i_loc * 66 + o_loc;
    t0[0 * 64 * 66] = f2bf(sb[io]);
    t0[1 * 64 * 66] = f2bf(a.x * sspv);
    t0[2 * 64 * 66] = f2bf(a.y * sspv);
    t0[3 * 64 * 66] = f2bf(a.z * sspv);
    t0[4 * 64 * 66] = f2bf(a.w * sspv);
    t0[5 * 64 * 66] = f2bf(b.x * sspv);
    t0[6 * 64 * 66] = f2bf(b.y * sspv);
    t0[7 * 64 * 66] = f2bf(b.z * sspv);
    t0[8 * 64 * 66] = f2bf(b.w * sspv);
  }
  __syncthreads();
  #pragma unroll
  for (int f = 0; f < 9; ++f)                  // write: lanes along i (coalesced)
    #pragma unroll 2
    for (int pass = 0; pass < 8; ++pass) {
      const int i_loc = tid & 63;
      const int o_loc = pass * 8 + (tid >> 6);
      Wt[((size_t)l * O + o0 + o_loc) * KD + f * 512 + i0 + i_loc] =
          T[(f * 64 + i_loc) * 66 + o_loc];
    }
}

// ---------- GEMM: 128x128 tile, BK=64, 8 waves, 3-deep counted vmcnt ----------
__device__ __forceinline__ void stage_tile8(const u16* __restrict__ A, const u16* __restrict__ Bt,
                                            u16* As, u16* Bs, int rowBase, int colBase,
                                            int kOff, int wave, int lane) {
  const int sRow   = lane >> 3;
  const int sChunk = (lane & 7) ^ sRow;        // pre-swizzled global 16B chunk
  #pragma unroll
  for (int j = 0; j < 2; ++j) {
    const int slot = wave * 16 + j * 8;        // 8 rows / gload_lds
    load_lds16(A  + (size_t)(rowBase + slot + sRow) * KD + kOff + sChunk * 8, As + slot * 64);
    load_lds16(Bt + (size_t)(colBase + slot + sRow) * KD + kOff + sChunk * 8, Bs + slot * 64);
  }
}

__device__ __forceinline__ void mma_step8(const u16* As, const u16* Bs, f32x4 acc[4][2],
                                          int wr, int wc, int lane) {
  const int lr = lane & 15, lk8 = lane >> 4;
  #pragma unroll
  for (int ks = 0; ks < 2; ++ks) {
    short8 af[4], bf[2];
    const int kc = ks * 4 + lk8;
    #pragma unroll
    for (int m = 0; m < 4; ++m) {
      const int r = wr * 64 + m * 16 + lr;
      af[m] = *(const short8*)(As + r * 64 + ((kc ^ (r & 7)) * 8));
    }
    #pragma unroll
    for (int n = 0; n < 2; ++n) {
      const int r = wc * 32 + n * 16 + lr;
      bf[n] = *(const short8*)(Bs + r * 64 + ((kc ^ (r & 7)) * 8));
    }
    #pragma unroll
    for (int m = 0; m < 4; ++m)
      #pragma unroll
      for (int n = 0; n < 2; ++n)
        acc[m][n] = __builtin_amdgcn_mfma_f32_16x16x32_bf16(af[m], bf[n], acc[m][n], 0, 0, 0);
  }
}

template<int N, int KITER>
__device__ __forceinline__ void gemm_job8(const u16* __restrict__ A, const u16* __restrict__ Bt,
                                          float* __restrict__ Cp, int bx, int by, int bz,
                                          u16* sm) {
  const int tid  = threadIdx.x;
  const int wave = tid >> 6, lane = tid & 63;
  const int rowBase = bx * 128, colBase = by * 128;
  const int kb0 = bz * KITER;
  const int wr = wave >> 2, wc = wave & 3;     // 2x4 wave grid: 64x32 each

  u16 *Ac = sm,             *Bc = sm + 8192;
  u16 *An = sm + 2 * 8192,  *Bn = sm + 3 * 8192;
  u16 *Af = sm + 4 * 8192,  *Bf = sm + 5 * 8192;

  f32x4 acc[4][2] = {};

  stage_tile8(A, Bt, Ac, Bc, rowBase, colBase, (kb0 + 0) * 64, wave, lane);
  stage_tile8(A, Bt, An, Bn, rowBase, colBase, (kb0 + 1) * 64, wave, lane);

  for (int t = 0; t < KITER - 1; ++t) {
    asm volatile("s_waitcnt vmcnt(4)" ::: "memory");   // tile t done; t+1 in flight
    __builtin_amdgcn_s_barrier();
    if (t + 2 < KITER)
      stage_tile8(A, Bt, Af, Bf, rowBase, colBase, (kb0 + t + 2) * 64, wave, lane);
    mma_step8(Ac, Bc, acc, wr, wc, lane);
    __builtin_amdgcn_s_barrier();
    u16* tp;
    tp = Ac; Ac = An; An = Af; Af = tp;
    tp = Bc; Bc = Bn; Bn = Bf; Bf = tp;
  }
  asm volatile("s_waitcnt vmcnt(0)" ::: "memory");
  __builtin_amdgcn_s_barrier();
  mma_step8(Ac, Bc, acc, wr, wc, lane);

  float* out = Cp + (size_t)bz * (size_t)NB * N;
  #pragma unroll
  for (int m = 0; m < 4; ++m) {
    const int row0 = rowBase + wr * 64 + m * 16 + (lane >> 4) * 4;   // row=(l>>4)*4+reg
    #pragma unroll
    for (int n = 0; n < 2; ++n) {
      const int col = colBase + wc * 32 + n * 16 + (lane & 15);      // col=l&15
      #pragma unroll
      for (int r = 0; r < 4; ++r)
        out[(size_t)(row0 + r) * N + col] = acc[m][n][r];
    }
  }
}

// ---------- mega ----------
__global__ __launch_bounds__(512, 1)
void mega(const float* __restrict__ x,
          const float* __restrict__ coef_fc, const float* __restrict__ sb_fc,
          const float* __restrict__ ssp_fc,  const float* __restrict__ coef_th,
          const float* __restrict__ sb_th,   const float* __restrict__ ssp_th,
          float* __restrict__ out, int* __restrict__ bar,
          u16* __restrict__ WtFc, u16* __restrict__ WtTh, u16* __restrict__ Act,
          float* __restrict__ Part, float* __restrict__ S) {
  const int tid = threadIdx.x, blk = blockIdx.x;
  __shared__ __align__(16) u16 sm[6 * 8192];   // 96 KiB (GEMM 3x dbuf / pack T / proj Ts)

  // ---- phase A: weight pack + S + expand0 ----
  {
    const int l  = blk >> 6;
    const int i0 = ((blk >> 3) & 7) * 64;
    const int o0 = (blk & 7) * 64;
    pack_tile(coef_fc, sb_fc, ssp_fc, WtFc, sm, l, i0, o0, 512);
    if (blk < 16) {
      __syncthreads();
      pack_tile(coef_th, sb_th, ssp_th, WtTh, sm, 0, (blk >> 1) * 64, (blk & 1) * 64, 128);
    } else if (blk < 36) {
      const int base = (blk - 16) * 4096;
      #pragma unroll
      for (int q = 0; q < 8; ++q) {
        const int id = base + q * 512 + tid;   // < 81920 = 128*640
        const int j = id & 127, t = id >> 7;
        const int m = ((j & 63) * t) % 63;
        const float ang = (float)(6.283185307179586 * (double)m / 63.0);
        S[(size_t)j * NTT + t] = (j < 64) ? cosf(ang) : sinf(ang);
      }
    }
    #pragma unroll
    for (int q = 0; q < 2; ++q) {              // expand0
      const int qid = blk * 1024 + q * 512 + tid;
      const int b = qid >> 7, i0q = (qid & 127) * 4;
      const float4 v = *(const float4*)(x + (size_t)qid * 4);
      float xv[4] = {v.x, v.y, v.z, v.w};
      expand_quad(xv, Act + (size_t)b * KD, i0q);
    }
  }
  gbar(bar);

  // ---- fc layers: 256 GEMM jobs (16bx x 4by x 4bz, XCD swizzle), then expand ----
  for (int l = 0; l < 4; ++l) {
    {
      const int xcd = blk & 7;
      const int bz  = xcd >> 1;
      const int u   = blk >> 3;
      const int bx  = ((u & 7) << 1) | (xcd & 1);
      const int by  = u >> 3;
      gemm_job8<512, 18>(Act, WtFc + (size_t)l * 512 * KD, Part, bx, by, bz, sm);
    }
    gbar(bar);
    #pragma unroll
    for (int q = 0; q < 2; ++q) {
      const int qid = blk * 1024 + q * 512 + tid;
      const int b = qid >> 7, i0q = (qid & 127) * 4;
      float xv[4] = {0.f, 0.f, 0.f, 0.f};
      #pragma unroll
      for (int t = 0; t < 4; ++t) {
        const float4 v = *(const float4*)(Part + (size_t)t * NB * 512 + (size_t)qid * 4);
        xv[0] += v.x; xv[1] += v.y; xv[2] += v.z; xv[3] += v.w;
      }
      expand_quad(xv, Act + (size_t)b * KD, i0q);
    }
    gbar(bar);
  }

  // ---- theta GEMM: 128 jobs (16bx x 8bz), kIter 9 ----
  if (blk < 128)
    gemm_job8<NTH, 9>(Act, WtTh, Part, blk & 15, 0, blk >> 4, sm);
  gbar(bar);

  // ---- proj (+8-partial theta reduce): 320 jobs ----
  float* Ts = (float*)sm;                      // [64][129] fp32 = 33 KB
  #pragma unroll
  for (int jq = 0; jq < 2; ++jq) {
    const int j = blk + jq * 256;
    if (j >= 320) break;
    const int brow = (j & 31) * 64, bcol = (j >> 5) * 64;
    for (int idx = tid; idx < 64 * 128; idx += 512) {
      const int r = idx >> 7, c = idx & 127;
      float s = 0.f;
      #pragma unroll
      for (int t = 0; t < 8; ++t)
        s += Part[(size_t)t * NB * NTH + (size_t)(brow + r) * NTH + c];
      Ts[r * 129 + c] = s;
    }
    __syncthreads();
    const int tx = tid & 15, ty = tid >> 4;    // 16 x 32
    const int r0 = ty * 2, c0 = tx * 4;
    float acc[2][4] = {};
    for (int k = 0; k < 128; ++k) {
      const float4 sv = *(const float4*)(S + (size_t)k * NTT + bcol + c0);
      #pragma unroll
      for (int rr = 0; rr < 2; ++rr) {
        const float tv = Ts[(r0 + rr) * 129 + k];
        acc[rr][0] += tv * sv.x; acc[rr][1] += tv * sv.y;
        acc[rr][2] += tv * sv.z; acc[rr][3] += tv * sv.w;
      }
    }
    #pragma unroll
    for (int rr = 0; rr < 2; ++rr) {
      const int b = brow + r0 + rr;
      #pragma unroll
      for (int cc = 0; cc < 4; ++cc) {
        const int t = bcol + c0 + cc;
        if (t < 512) out[(size_t)b * 512 + t] = acc[rr][cc];                            // backcast
        else         out[(size_t)NB * 512 + (size_t)b * NTH + (t - 512)] = acc[rr][cc]; // forecast
      }
    }
    __syncthreads();
  }
}

extern "C" void kernel_launch(void* const* d_in, const int* in_sizes, int n_in,
                              void* d_out, int out_size, void* d_ws, size_t ws_size,
                              hipStream_t stream) {
  (void)in_sizes; (void)n_in; (void)out_size; (void)ws_size;
  const float* x       = (const float*)d_in[0];
  const float* coef_fc = (const float*)d_in[1];
  const float* sb_fc   = (const float*)d_in[2];
  const float* ssp_fc  = (const float*)d_in[3];
  const float* coef_th = (const float*)d_in[4];
  const float* sb_th   = (const float*)d_in[5];
  const float* ssp_th  = (const float*)d_in[6];
  float* out = (float*)d_out;

  // ws: bar 256B | WtFc 18.9M | WtTh 1.18M | Act 18.9M | Part 16.8M | S 0.33M
  int*  bar  = (int*)d_ws;
  u16*  WtFc = (u16*)((char*)d_ws + 256);
  u16*  WtTh = WtFc + (size_t)4 * 512 * KD;
  u16*  Act  = WtTh + (size_t)NTH * KD;
  float* Part = (float*)(Act + (size_t)NB * KD);
  float* S    = Part + (size_t)4 * NB * 512;

  hipMemsetAsync(bar, 0, 256, stream);
  mega<<<dim3(GRID), dim3(512), 0, stream>>>(x, coef_fc, sb_fc, ssp_fc,
                                             coef_th, sb_th, ssp_th,
                                             out, bar, WtFc, WtTh, Act, Part, S);
}

// Round 10
// 253.968 us; speedup vs baseline: 5.7662x; 1.8496x over previous
//
#include <hip/hip_runtime.h>
#include <stdint.h>

// NBEATS seasonal KAN block — multi-kernel, full-K 64x64 GEMM with FUSED
// expand epilogue (no split-K Part round-trip). 7 dispatches. ws ~60 MB.

typedef unsigned short u16;
typedef __attribute__((ext_vector_type(8))) short short8;   // 8 bf16
typedef __attribute__((ext_vector_type(4))) float f32x4;    // MFMA accum

#define NB 2048
#define KD 4608
#define NTH 128
#define NTT 640

__device__ __forceinline__ u16 f2bf(float f) {
  union { float f; uint32_t u; } c; c.f = f;
  return (u16)((c.u + 0x7FFFu + ((c.u >> 16) & 1u)) >> 16);   // RNE
}

__device__ __forceinline__ void load_lds16(const void* g, void* lds) {
  __builtin_amdgcn_global_load_lds((const __attribute__((address_space(1))) void*)g,
                                   (__attribute__((address_space(3))) void*)lds, 16, 0, 0);
}

// ---------- bspline (K=3, NUM=5, uniform grid g[j]=0.4j-2.2), div-free ----------
__device__ __forceinline__ void bspline8(float x, float* v8) {
  float g[12];
  #pragma unroll
  for (int j = 0; j < 12; ++j) g[j] = (float)((j - 3) * 0.4 - 1.0);
  float w[11];
  #pragma unroll
  for (int j = 0; j < 11; ++j) w[j] = (x >= g[j] && x < g[j+1]) ? 1.0f : 0.0f;
  #pragma unroll
  for (int p = 1; p <= 3; ++p) {
    #pragma unroll
    for (int j = 0; j < 11 - p; ++j) {
      const float i1 = 1.0f / (g[j+p] - g[j]);
      const float i2 = 1.0f / (g[j+p+1] - g[j+1]);
      w[j] = (x - g[j]) * i1 * w[j] + (g[j+p+1] - x) * i2 * w[j+1];
    }
  }
  #pragma unroll
  for (int j = 0; j < 8; ++j) v8[j] = w[j];
}

__device__ __forceinline__ void expand_quad(const float* xv, u16* __restrict__ row, int i0) {
  float base[4], v[4][8];
  #pragma unroll
  for (int e = 0; e < 4; ++e) {
    base[e] = xv[e] / (1.0f + __expf(-xv[e]));   // silu
    bspline8(xv[e], v[e]);
  }
  short4 s;
  s.x = (short)f2bf(base[0]); s.y = (short)f2bf(base[1]);
  s.z = (short)f2bf(base[2]); s.w = (short)f2bf(base[3]);
  *(short4*)(row + i0) = s;
  #pragma unroll
  for (int f = 0; f < 8; ++f) {
    s.x = (short)f2bf(v[0][f]); s.y = (short)f2bf(v[1][f]);
    s.z = (short)f2bf(v[2][f]); s.w = (short)f2bf(v[3][f]);
    *(short4*)(row + (1 + f) * 512 + i0) = s;
  }
}

// ---------- setup: weight pack (LDS transpose) + seasonal basis + expand0 ----------
// blocks 0..255: fc tiles | 256..271: th tiles | 272..291: S | 292..547: expand0
__global__ __launch_bounds__(256)
void setup_kernel(const float* __restrict__ coef_fc, const float* __restrict__ sb_fc,
                  const float* __restrict__ ssp_fc,  const float* __restrict__ coef_th,
                  const float* __restrict__ sb_th,   const float* __restrict__ ssp_th,
                  const float* __restrict__ x,
                  u16* __restrict__ WtFc, u16* __restrict__ WtTh,
                  float* __restrict__ S,  u16* __restrict__ Act) {
  const int blk = blockIdx.x, tid = threadIdx.x;
  __shared__ u16 T[9 * 64 * 66];                 // 76 KB, pad 66
  if (blk < 272) {
    const float *coef, *sb, *ssp; u16* Wt; int O, l, i0, o0;
    if (blk < 256) {
      coef = coef_fc; sb = sb_fc; ssp = ssp_fc; Wt = WtFc; O = 512;
      l = blk >> 6; i0 = ((blk >> 3) & 7) * 64; o0 = (blk & 7) * 64;
    } else {
      coef = coef_th; sb = sb_th; ssp = ssp_th; Wt = WtTh; O = 128;
      const int t = blk - 256;
      l = 0; i0 = (t >> 1) * 64; o0 = (t & 1) * 64;
    }
    #pragma unroll 4
    for (int pass = 0; pass < 16; ++pass) {      // read: lanes along o (coalesced)
      const int o_loc = tid & 63;
      const int i_loc = pass * 4 + (tid >> 6);
      const size_t io = ((size_t)l * 512 + i0 + i_loc) * (size_t)O + o0 + o_loc;
      const float sspv = ssp[io];
      const float4 a = *(const float4*)(coef + io * 8);
      const float4 b = *(const float4*)(coef + io * 8 + 4);
      u16* t0 = T + i_loc * 66 + o_loc;
      t0[0 * 64 * 66] = f2bf(sb[io]);
      t0[1 * 64 * 66] = f2bf(a.x * sspv);
      t0[2 * 64 * 66] = f2bf(a.y * sspv);
      t0[3 * 64 * 66] = f2bf(a.z * sspv);
      t0[4 * 64 * 66] = f2bf(a.w * sspv);
      t0[5 * 64 * 66] = f2bf(b.x * sspv);
      t0[6 * 64 * 66] = f2bf(b.y * sspv);
      t0[7 * 64 * 66] = f2bf(b.z * sspv);
      t0[8 * 64 * 66] = f2bf(b.w * sspv);
    }
    __syncthreads();
    #pragma unroll
    for (int f = 0; f < 9; ++f)                  // write: lanes along i (coalesced)
      #pragma unroll 4
      for (int pass = 0; pass < 16; ++pass) {
        const int i_loc = tid & 63;
        const int o_loc = pass * 4 + (tid >> 6);
        Wt[((size_t)l * O + o0 + o_loc) * KD + f * 512 + i0 + i_loc] =
            T[(f * 64 + i_loc) * 66 + o_loc];
      }
  } else if (blk < 292) {
    const int base = (blk - 272) * 4096;
    #pragma unroll 4
    for (int q = 0; q < 16; ++q) {
      const int id = base + q * 256 + tid;       // < 81920 = 128*640
      const int j = id & 127, t = id >> 7;
      const int m = ((j & 63) * t) % 63;
      const float ang = (float)(6.283185307179586 * (double)m / 63.0);
      S[(size_t)j * NTT + t] = (j < 64) ? cosf(ang) : sinf(ang);
    }
  } else {
    #pragma unroll
    for (int q = 0; q < 4; ++q) {                // expand0: 2048*128 quads
      const int qid = (blk - 292) * 1024 + q * 256 + tid;
      const int b = qid >> 7, i0 = (qid & 127) * 4;
      const float4 v = *(const float4*)(x + (size_t)qid * 4);
      float xv[4] = {v.x, v.y, v.z, v.w};
      expand_quad(xv, Act + (size_t)b * KD, i0);
    }
  }
}

// ---------- fused GEMM: 64x64 tile, full K (72 steps), 8 waves, 3-deep vmcnt ----------
// EXPAND: epilogue computes silu/bspline of C and writes bf16 Act (9 slices).
// else: writes fp32 theta rows.
template<bool EXPAND>
__global__ __launch_bounds__(512, 1)
void gemm_fused(const u16* __restrict__ A, const u16* __restrict__ Bt,
                u16* __restrict__ ActOut, float* __restrict__ ThOut) {
  __shared__ __align__(16) u16 smb[3 * 8192];    // 48 KB: 3 x (As 8KB | Bs 8KB)
  __shared__ __align__(16) float Cl[64 * 68];    // 17.4 KB, pad 68
  const int tid  = threadIdx.x;
  const int wave = tid >> 6, lane = tid & 63;
  int bx, by;
  if (EXPAND) {                                  // XCD-locality: 4 bx-panels per XCD
    const int xcd = blockIdx.x & 7, j = blockIdx.x >> 3;
    bx = xcd * 4 + (j & 3); by = j >> 2;         // 32 x 8
  } else {
    bx = blockIdx.x & 31; by = blockIdx.x >> 5;  // 32 x 2
  }
  const int rowBase = bx * 64, colBase = by * 64;
  const int wr = wave >> 2, wc = wave & 3;       // 2x4 wave grid: 32x16 per wave

  const int sRow   = lane >> 3;
  const int sChunk = (lane & 7) ^ sRow;          // pre-swizzled global 16B chunk
  const int slot   = wave * 8;                   // 8 rows per wave instr

  u16 *p0 = smb, *p1 = smb + 8192, *p2 = smb + 16384;
  f32x4 acc[2] = {};

  // prologue: tiles 0,1 (2 loads/thread each)
  {
    const u16* gA = A  + (size_t)(rowBase + slot + sRow) * KD + sChunk * 8;
    const u16* gB = Bt + (size_t)(colBase + slot + sRow) * KD + sChunk * 8;
    load_lds16(gA,      p0 + slot * 64);
    load_lds16(gB,      p0 + 4096 + slot * 64);
    load_lds16(gA + 64, p1 + slot * 64);
    load_lds16(gB + 64, p1 + 4096 + slot * 64);
  }

  for (int t = 0; t < 71; ++t) {
    asm volatile("s_waitcnt vmcnt(2)" ::: "memory");   // tile t landed; t+1 in flight
    __builtin_amdgcn_s_barrier();
    if (t + 2 < 72) {
      const int kOff = (t + 2) * 64;
      load_lds16(A  + (size_t)(rowBase + slot + sRow) * KD + kOff + sChunk * 8,
                 p2 + slot * 64);
      load_lds16(Bt + (size_t)(colBase + slot + sRow) * KD + kOff + sChunk * 8,
                 p2 + 4096 + slot * 64);
    }
    {
      const u16* As = p0;
      const u16* Bs = p0 + 4096;
      #pragma unroll
      for (int ks = 0; ks < 2; ++ks) {
        const int kc = ks * 4 + (lane >> 4);
        short8 af[2], bf;
        #pragma unroll
        for (int m = 0; m < 2; ++m) {
          const int r = wr * 32 + m * 16 + (lane & 15);
          af[m] = *(const short8*)(As + r * 64 + ((kc ^ (r & 7)) * 8));
        }
        {
          const int r = wc * 16 + (lane & 15);
          bf = *(const short8*)(Bs + r * 64 + ((kc ^ (r & 7)) * 8));
        }
        #pragma unroll
        for (int m = 0; m < 2; ++m)
          acc[m] = __builtin_amdgcn_mfma_f32_16x16x32_bf16(af[m], bf, acc[m], 0, 0, 0);
      }
    }
    __builtin_amdgcn_s_barrier();
    u16* tp = p0; p0 = p1; p1 = p2; p2 = tp;
  }
  asm volatile("s_waitcnt vmcnt(0)" ::: "memory");     // final tile (71)
  __builtin_amdgcn_s_barrier();
  {
    const u16* As = p0;
    const u16* Bs = p0 + 4096;
    #pragma unroll
    for (int ks = 0; ks < 2; ++ks) {
      const int kc = ks * 4 + (lane >> 4);
      short8 af[2], bf;
      #pragma unroll
      for (int m = 0; m < 2; ++m) {
        const int r = wr * 32 + m * 16 + (lane & 15);
        af[m] = *(const short8*)(As + r * 64 + ((kc ^ (r & 7)) * 8));
      }
      {
        const int r = wc * 16 + (lane & 15);
        bf = *(const short8*)(Bs + r * 64 + ((kc ^ (r & 7)) * 8));
      }
      #pragma unroll
      for (int m = 0; m < 2; ++m)
        acc[m] = __builtin_amdgcn_mfma_f32_16x16x32_bf16(af[m], bf, acc[m], 0, 0, 0);
    }
  }

  // epilogue: C -> LDS (transposed access), then expand or copy out
  #pragma unroll
  for (int m = 0; m < 2; ++m) {
    const int row = wr * 32 + m * 16 + (lane >> 4) * 4;   // C/D: row=(l>>4)*4+reg
    const int col = wc * 16 + (lane & 15);                // C/D: col=l&15
    #pragma unroll
    for (int r = 0; r < 4; ++r)
      Cl[(row + r) * 68 + col] = acc[m][r];
  }
  __syncthreads();
  #pragma unroll
  for (int pass = 0; pass < 2; ++pass) {
    const int q = pass * 512 + tid;              // 0..1023 = 64 rows x 16 quads
    const int b_loc = q >> 4, o4 = (q & 15) * 4;
    const float4 v = *(const float4*)(Cl + b_loc * 68 + o4);
    if (EXPAND) {
      float xv[4] = {v.x, v.y, v.z, v.w};
      expand_quad(xv, ActOut + (size_t)(rowBase + b_loc) * KD, colBase + o4);
    } else {
      *(float4*)(ThOut + (size_t)(rowBase + b_loc) * NTH + colBase + o4) = v;
    }
  }
}

// ---------- proj: out = theta(2048x128) @ S(128x640) ----------
__global__ __launch_bounds__(256)
void proj_kernel(const float* __restrict__ theta, const float* __restrict__ S,
                 float* __restrict__ out) {
  __shared__ float Ts[64][129];
  const int tid = threadIdx.x;
  const int brow = blockIdx.x * 64, bcol = blockIdx.y * 64;
  for (int idx = tid; idx < 64 * 128; idx += 256) {
    const int r = idx >> 7, c = idx & 127;
    Ts[r][c] = theta[(size_t)(brow + r) * NTH + c];
  }
  __syncthreads();
  const int tx = tid & 15, ty = tid >> 4;
  const int r0 = ty * 4, c0 = tx * 4;
  float acc[4][4] = {};
  for (int k = 0; k < 128; ++k) {
    const float4 sv = *(const float4*)(S + (size_t)k * NTT + bcol + c0);
    #pragma unroll
    for (int rr = 0; rr < 4; ++rr) {
      const float tv = Ts[r0 + rr][k];
      acc[rr][0] += tv * sv.x; acc[rr][1] += tv * sv.y;
      acc[rr][2] += tv * sv.z; acc[rr][3] += tv * sv.w;
    }
  }
  #pragma unroll
  for (int rr = 0; rr < 4; ++rr) {
    const int b = brow + r0 + rr;
    #pragma unroll
    for (int cc = 0; cc < 4; ++cc) {
      const int t = bcol + c0 + cc;
      if (t < 512) out[(size_t)b * 512 + t] = acc[rr][cc];                            // backcast
      else         out[(size_t)NB * 512 + (size_t)b * NTH + (t - 512)] = acc[rr][cc]; // forecast
    }
  }
}

extern "C" void kernel_launch(void* const* d_in, const int* in_sizes, int n_in,
                              void* d_out, int out_size, void* d_ws, size_t ws_size,
                              hipStream_t stream) {
  (void)in_sizes; (void)n_in; (void)out_size; (void)ws_size;
  const float* x       = (const float*)d_in[0];
  const float* coef_fc = (const float*)d_in[1];
  const float* sb_fc   = (const float*)d_in[2];
  const float* ssp_fc  = (const float*)d_in[3];
  const float* coef_th = (const float*)d_in[4];
  const float* sb_th   = (const float*)d_in[5];
  const float* ssp_th  = (const float*)d_in[6];
  float* out = (float*)d_out;

  // ws: WtFc 18.9M | WtTh 1.18M | ActA 18.9M | ActB 18.9M | theta 1.05M | S 0.33M
  u16*  WtFc  = (u16*)d_ws;
  u16*  WtTh  = WtFc + (size_t)4 * 512 * KD;
  u16*  ActA  = WtTh + (size_t)NTH * KD;
  u16*  ActB  = ActA + (size_t)NB * KD;
  float* theta = (float*)(ActB + (size_t)NB * KD);
  float* S     = theta + (size_t)NB * NTH;

  setup_kernel<<<dim3(548), dim3(256), 0, stream>>>(coef_fc, sb_fc, ssp_fc,
                                                    coef_th, sb_th, ssp_th, x,
                                                    WtFc, WtTh, S, ActA);
  u16* Acur = ActA; u16* Anext = ActB;
  for (int l = 0; l < 4; ++l) {
    gemm_fused<true><<<dim3(256), dim3(512), 0, stream>>>(
        Acur, WtFc + (size_t)l * 512 * KD, Anext, nullptr);
    u16* tp = Acur; Acur = Anext; Anext = tp;
  }
  gemm_fused<false><<<dim3(64), dim3(512), 0, stream>>>(Acur, WtTh, nullptr, theta);
  proj_kernel<<<dim3(32, 10), dim3(256), 0, stream>>>(theta, S, out);
}